// Round 9
// baseline (466.634 us; speedup 1.0000x reference)
//
#include <hip/hip_runtime.h>

#define N_NODES 100000
#define N_EDGES 800000
#define DF 64
#define NGRAPH 512
#define LDIM 192   // L * D
#define BN_EPS 1e-5
#define NTILES 6250      // N_NODES / 16
#define GIN_GRID 1563    // ceil(NTILES / 4 waves)
#define NWT (GIN_GRID * 4)   // partial-stat slots (one per wave)
#define COLS_CAP 2600000     // sum of padded degrees < 2.4M
#define NBUCK 782            // ceil(N_NODES / 128)
#define BCAP 2048            // max edges per bucket (avg 1023, 32 sigma head)

typedef __attribute__((ext_vector_type(8))) short bf16x8;
typedef __attribute__((ext_vector_type(4))) float f32x4;

__device__ inline short f2bf(float x) {
    union { float f; unsigned u; } v; v.f = x;
    unsigned r = v.u + 0x7fff + ((v.u >> 16) & 1);   // RNE
    return (short)(r >> 16);
}

__device__ inline int pdeg_of(int d) {   // pad to multiple of 16, min 16
    int p = (d + 15) & ~15;
    return p < 16 ? 16 : p;
}

// ---------------------------------------------------------------------------
// Bucketed CSR build. bucket = row >> 7 (128 rows per bucket).
// ---------------------------------------------------------------------------
__global__ __launch_bounds__(256) void bucket_scatter_kernel(
    const int* __restrict__ ei, int* __restrict__ cur,
    unsigned* __restrict__ bucketData)
{
    int e = blockIdx.x * 256 + threadIdx.x;
    if (e >= N_EDGES) return;
    int r = ei[e];
    int c = ei[N_EDGES + e];
    int b = r >> 7;
    int pos = atomicAdd(&cur[b], 1);
    bucketData[b * BCAP + pos] = ((unsigned)(r & 127) << 17) | (unsigned)c;
}

__global__ __launch_bounds__(256) void bucket_count_kernel(
    const unsigned* __restrict__ bucketData, const int* __restrict__ cur,
    int* __restrict__ deg, int* __restrict__ bpad)
{
    __shared__ int rc[128];
    __shared__ int red[4];
    int b = blockIdx.x, tid = threadIdx.x;
    int rowbase = b << 7;
    int nrows = min(128, N_NODES - rowbase);
    int cnt = cur[b];
    if (tid < 128) rc[tid] = 0;
    __syncthreads();
    for (int e = tid; e < cnt; e += 256)
        atomicAdd(&rc[bucketData[b * BCAP + e] >> 17], 1);
    __syncthreads();
    int v = 0;
    if (tid < nrows) {
        int d = rc[tid];
        deg[rowbase + tid] = d;
        v = pdeg_of(d);
    }
    #pragma unroll
    for (int o = 32; o > 0; o >>= 1) v += __shfl_down(v, o, 64);
    if ((tid & 63) == 0) red[tid >> 6] = v;
    __syncthreads();
    if (tid == 0) bpad[b] = red[0] + red[1] + red[2] + red[3];
}

__global__ __launch_bounds__(1024) void bucket_scan_kernel(
    const int* __restrict__ bpad, int* __restrict__ bbase)
{
    __shared__ int buf[1024];
    int tid = threadIdx.x;
    int own = (tid < NBUCK) ? bpad[tid] : 0;
    buf[tid] = own;
    __syncthreads();
    for (int o = 1; o < 1024; o <<= 1) {
        int t = (tid >= o) ? buf[tid - o] : 0;
        __syncthreads();
        buf[tid] += t;
        __syncthreads();
    }
    if (tid < NBUCK) bbase[tid] = buf[tid] - own;
}

__global__ __launch_bounds__(256) void bucket_emit_kernel(
    const unsigned* __restrict__ bucketData, const int* __restrict__ cur,
    const int* __restrict__ bbase,
    int* __restrict__ off, int* __restrict__ colS)
{
    __shared__ int rc[128], rstart[128], rcur[128], sbuf[128];
    __shared__ int region[4096];
    int b = blockIdx.x, tid = threadIdx.x;
    int rowbase = b << 7;
    int nrows = min(128, N_NODES - rowbase);
    int cnt = cur[b];
    int base = bbase[b];
    if (tid < 128) rc[tid] = 0;
    __syncthreads();
    for (int e = tid; e < cnt; e += 256)
        atomicAdd(&rc[bucketData[b * BCAP + e] >> 17], 1);
    __syncthreads();
    int pd = (tid < nrows) ? pdeg_of(rc[tid]) : 0;
    if (tid < 128) sbuf[tid] = pd;
    __syncthreads();
    for (int o = 1; o < 128; o <<= 1) {
        int t = 0;
        if (tid < 128 && tid >= o) t = sbuf[tid - o];
        __syncthreads();
        if (tid < 128) sbuf[tid] += t;
        __syncthreads();
    }
    if (tid < 128) { rstart[tid] = sbuf[tid] - pd; rcur[tid] = sbuf[tid] - pd; }
    __syncthreads();
    int total = sbuf[127];
    // place real edges
    for (int e = tid; e < cnt; e += 256) {
        unsigned p = bucketData[b * BCAP + e];
        int lr = p >> 17;
        int c = p & 0x1FFFF;
        int pos = atomicAdd(&rcur[lr], 1);
        region[pos] = c * DF;
    }
    __syncthreads();
    // pads point at the node's own row (corrected algebraically in gather)
    for (int i = tid; i < nrows; i += 256) {
        int st = rstart[i] + rc[i];
        int en = rstart[i] + pdeg_of(rc[i]);
        int sent = (rowbase + i) * DF;
        for (int j = st; j < en; ++j) region[j] = sent;
    }
    __syncthreads();
    for (int k = tid; k < total; k += 256) colS[base + k] = region[k];
    if (tid < nrows) off[rowbase + tid] = base + rstart[tid];
    if (b == NBUCK - 1 && tid == 0) off[N_NODES] = base + total;
}

// ---------------------------------------------------------------------------
__global__ __launch_bounds__(256) void gstart_kernel(
    const int* __restrict__ batch, int* __restrict__ gstart)
{
    int g = blockIdx.x * 256 + threadIdx.x;
    if (g > NGRAPH) return;
    if (g == NGRAPH) { gstart[g] = N_NODES; return; }
    int lo = 0, hi = N_NODES;
    while (lo < hi) {
        int mid = (lo + hi) >> 1;
        if (batch[mid] < g) lo = mid + 1; else hi = mid;
    }
    gstart[g] = lo;
}

__global__ void init_id_kernel(float* __restrict__ idsc, float* __restrict__ idsh)
{
    int f = threadIdx.x;
    idsc[f] = 1.0f;
    idsh[f] = 0.0f;
}

// ---------------------------------------------------------------------------
// Pack W (fp32 [64][64], z@W) into MFMA B-fragment order, bf16.
// ---------------------------------------------------------------------------
__global__ __launch_bounds__(256) void pack_w_kernel(
    const float* __restrict__ W1, const float* __restrict__ W2,
    short* __restrict__ Wpk)
{
    int u = blockIdx.x;            // 0..5 = layer*2 + gemm
    int layer = u >> 1, gm = u & 1;
    const float* W = (gm ? W2 : W1) + layer * 4096;
    short* dst = Wpk + u * 4096;
    for (int idx = threadIdx.x; idx < 4096; idx += 256) {
        int i = idx & 7;
        int l = (idx >> 3) & 63;
        int rest = idx >> 9;       // nt*2+kt
        int kt = rest & 1, nt = rest >> 1;
        int k = kt * 32 + (l >> 4) * 8 + i;
        int n = nt * 16 + (l & 15);
        dst[idx] = f2bf(W[k * 64 + n]);
    }
}

// ---------------------------------------------------------------------------
// Fused GIN layer (MFMA). One 16-node tile per wave. Branchless padded
// gather with scalar (SALU) addressing; prev-layer BN folded in:
//   z = sc*((1+eps-npad)*zp_n + sum_all) + (1+eps+deg)*sh
// ---------------------------------------------------------------------------
__global__ __launch_bounds__(256) void gin_layer_kernel(
    const float* __restrict__ zp,       // prev z3 (or x for layer 0)
    const float* __restrict__ sc_in,    // prev BN scale (or 1.0)
    const float* __restrict__ sh_in,    // prev BN shift (or 0.0)
    const int* __restrict__ off,        // padded CSR offsets
    const int* __restrict__ deg,        // real degrees
    const int* __restrict__ colS,       // element offsets (c*64), padded
    float* __restrict__ zout,
    const short* __restrict__ Wpk,      // this layer: [2][4096]
    const float* __restrict__ b1,
    const float* __restrict__ b2,
    const float* __restrict__ gin_eps,
    const float* __restrict__ gin_bias,
    float* __restrict__ part_s,         // [64][NWT]
    float* __restrict__ part_q)
{
    __shared__ __align__(16) short Wp1s[4096];
    __shared__ __align__(16) short Wp2s[4096];
    __shared__ __align__(16) short zs[4][16 * 72];   // z, then z1 (wave-private)

    int tid = threadIdx.x;
    {   // stage packed weights (16 KB), once per block
        const short4* s1 = (const short4*)Wpk;
        const short4* s2 = (const short4*)(Wpk + 4096);
        short4* d1 = (short4*)Wp1s;
        short4* d2 = (short4*)Wp2s;
        for (int i = tid; i < 1024; i += 256) { d1[i] = s1[i]; d2[i] = s2[i]; }
    }

    int w = tid >> 6, l = tid & 63;
    int lr = l & 15;    // A-row / B-col / D-col low index
    int lk = l >> 4;    // k-group / D-row group
    float epsf = 1.0f + gin_eps[0];
    float scf = sc_in[l], shf = sh_in[l];
    float b1f[4], b2f[4], gbf[4];
    #pragma unroll
    for (int nt = 0; nt < 4; ++nt) {
        b1f[nt] = b1[nt * 16 + lr];
        b2f[nt] = b2[nt * 16 + lr];
        gbf[nt] = gin_bias[nt * 16 + lr];
    }
    float ssum[4] = {0, 0, 0, 0}, sq[4] = {0, 0, 0, 0};
    short* zw = zs[w];
    __syncthreads();

    int t = blockIdx.x * 4 + w;
    bool active = t < NTILES;
    int n0 = t * 16;

    if (active) {
        // ---- gather: 2 nodes in flight (32 loads), branchless first batch --
        #pragma unroll 1
        for (int mp = 0; mp < 8; ++mp) {
            int nodeA = n0 + (mp << 1);
            int nodeB = nodeA + 1;
            int sA = __builtin_amdgcn_readfirstlane(off[nodeA]);
            int eA = __builtin_amdgcn_readfirstlane(off[nodeA + 1]);
            int dA = __builtin_amdgcn_readfirstlane(deg[nodeA]);
            int sB = __builtin_amdgcn_readfirstlane(off[nodeB]);
            int eB = __builtin_amdgcn_readfirstlane(off[nodeB + 1]);
            int dB = __builtin_amdgcn_readfirstlane(deg[nodeB]);
            float hnA = zp[nodeA * DF + l];
            float hnB = zp[nodeB * DF + l];
            float vA[16], vB[16];
            #pragma unroll
            for (int j = 0; j < 16; ++j) {
                int co = __builtin_amdgcn_readfirstlane(colS[sA + j]);
                vA[j] = zp[co + l];
            }
            #pragma unroll
            for (int j = 0; j < 16; ++j) {
                int co = __builtin_amdgcn_readfirstlane(colS[sB + j]);
                vB[j] = zp[co + l];
            }
            float aA0 = (vA[0] + vA[1]) + (vA[2] + vA[3]);
            float aA1 = (vA[4] + vA[5]) + (vA[6] + vA[7]);
            float aA2 = (vA[8] + vA[9]) + (vA[10] + vA[11]);
            float aA3 = (vA[12] + vA[13]) + (vA[14] + vA[15]);
            float accA = (aA0 + aA1) + (aA2 + aA3);
            float aB0 = (vB[0] + vB[1]) + (vB[2] + vB[3]);
            float aB1 = (vB[4] + vB[5]) + (vB[6] + vB[7]);
            float aB2 = (vB[8] + vB[9]) + (vB[10] + vB[11]);
            float aB3 = (vB[12] + vB[13]) + (vB[14] + vB[15]);
            float accB = (aB0 + aB1) + (aB2 + aB3);
            // rare remainder (deg > 16): ~0.4% of nodes
            for (int i = sA + 16; i < eA; i += 16) {
                #pragma unroll
                for (int j = 0; j < 16; ++j) {
                    int co = __builtin_amdgcn_readfirstlane(colS[i + j]);
                    accA += zp[co + l];
                }
            }
            for (int i = sB + 16; i < eB; i += 16) {
                #pragma unroll
                for (int j = 0; j < 16; ++j) {
                    int co = __builtin_amdgcn_readfirstlane(colS[i + j]);
                    accB += zp[co + l];
                }
            }
            float npA = (float)(eA - sA - dA);
            float npB = (float)(eB - sB - dB);
            float zfA = scf * ((epsf - npA) * hnA + accA) + (epsf + (float)dA) * shf;
            float zfB = scf * ((epsf - npB) * hnB + accB) + (epsf + (float)dB) * shf;
            zw[(mp * 2) * 72 + l] = f2bf(zfA);
            zw[(mp * 2 + 1) * 72 + l] = f2bf(zfB);
        }

        // ---- GEMM1: z1 = relu(z @ W1 + b1)  (z1 overwrites z rows) ----
        {
            bf16x8 a0 = *(const bf16x8*)&zw[lr * 72 + lk * 8];
            bf16x8 a1 = *(const bf16x8*)&zw[lr * 72 + 32 + lk * 8];
            #pragma unroll
            for (int nt = 0; nt < 4; ++nt) {
                f32x4 acc = {0.f, 0.f, 0.f, 0.f};
                bf16x8 bb0 = *(const bf16x8*)&Wp1s[((nt * 2 + 0) * 64 + l) * 8];
                bf16x8 bb1 = *(const bf16x8*)&Wp1s[((nt * 2 + 1) * 64 + l) * 8];
                acc = __builtin_amdgcn_mfma_f32_16x16x32_bf16(a0, bb0, acc, 0, 0, 0);
                acc = __builtin_amdgcn_mfma_f32_16x16x32_bf16(a1, bb1, acc, 0, 0, 0);
                #pragma unroll
                for (int r = 0; r < 4; ++r) {
                    float v = fmaxf(acc[r] + b1f[nt], 0.0f);
                    zw[(lk * 4 + r) * 72 + nt * 16 + lr] = f2bf(v);
                }
            }
        }

        // ---- GEMM2: z3 = relu(relu(z1 @ W2 + b2) + gin_bias) ----
        {
            bf16x8 a0 = *(const bf16x8*)&zw[lr * 72 + lk * 8];
            bf16x8 a1 = *(const bf16x8*)&zw[lr * 72 + 32 + lk * 8];
            #pragma unroll
            for (int nt = 0; nt < 4; ++nt) {
                f32x4 acc = {0.f, 0.f, 0.f, 0.f};
                bf16x8 bb0 = *(const bf16x8*)&Wp2s[((nt * 2 + 0) * 64 + l) * 8];
                bf16x8 bb1 = *(const bf16x8*)&Wp2s[((nt * 2 + 1) * 64 + l) * 8];
                acc = __builtin_amdgcn_mfma_f32_16x16x32_bf16(a0, bb0, acc, 0, 0, 0);
                acc = __builtin_amdgcn_mfma_f32_16x16x32_bf16(a1, bb1, acc, 0, 0, 0);
                #pragma unroll
                for (int r = 0; r < 4; ++r) {
                    float v = fmaxf(fmaxf(acc[r] + b2f[nt], 0.0f) + gbf[nt], 0.0f);
                    zout[(n0 + lk * 4 + r) * DF + nt * 16 + lr] = v;
                    ssum[nt] += v;
                    sq[nt] += v * v;
                }
            }
        }
    }

    // ---- per-wave BN partials (all waves write; zeros if inactive) ----
    #pragma unroll
    for (int nt = 0; nt < 4; ++nt) {
        float sv = ssum[nt], qv = sq[nt];
        sv += __shfl_xor(sv, 16, 64); sv += __shfl_xor(sv, 32, 64);
        qv += __shfl_xor(qv, 16, 64); qv += __shfl_xor(qv, 32, 64);
        if (l < 16) {
            part_s[(nt * 16 + l) * NWT + t] = sv;
            part_q[(nt * 16 + l) * NWT + t] = qv;
        }
    }
}

// ---------------------------------------------------------------------------
// Reduce per-wave partials -> BN scale/shift (one block per feature)
// ---------------------------------------------------------------------------
__global__ __launch_bounds__(256) void stat_reduce_kernel(
    const float* __restrict__ part_s, const float* __restrict__ part_q,
    const float* __restrict__ gamma, const float* __restrict__ beta,
    float* __restrict__ scale, float* __restrict__ shift)
{
    __shared__ double rs[4], rq[4];
    int f = blockIdx.x, tid = threadIdx.x;
    double s = 0.0, q = 0.0;
    for (int j = tid; j < NWT; j += 256) {
        s += (double)part_s[f * NWT + j];
        q += (double)part_q[f * NWT + j];
    }
    for (int o = 32; o > 0; o >>= 1) {
        s += __shfl_down(s, o, 64);
        q += __shfl_down(q, o, 64);
    }
    if ((tid & 63) == 0) { rs[tid >> 6] = s; rq[tid >> 6] = q; }
    __syncthreads();
    if (tid == 0) {
        double st = rs[0] + rs[1] + rs[2] + rs[3];
        double qt = rq[0] + rq[1] + rq[2] + rq[3];
        double mean = st / N_NODES;
        double var = qt / N_NODES - mean * mean;
        double inv = (double)gamma[f] / sqrt(var + BN_EPS);
        scale[f] = (float)inv;
        shift[f] = (float)((double)beta[f] - mean * inv);
    }
}

// ---------------------------------------------------------------------------
// Pool-only: pooled[g] = sc * sum_{nodes in g} z3 + cnt(g) * sh
// ---------------------------------------------------------------------------
__global__ __launch_bounds__(256) void pool_kernel(
    const float* __restrict__ z,
    const float* __restrict__ scale,
    const float* __restrict__ shift,
    const int* __restrict__ gstart,
    float* __restrict__ pooled,
    int layerOff)
{
    __shared__ float red[4][64];
    int g = blockIdx.x;
    int tid = threadIdx.x;
    int w = tid >> 6, f = tid & 63;

    int s = gstart[g], e = gstart[g + 1];
    float acc = 0.0f;
    for (int node = s + w; node < e; node += 4)
        acc += z[node * DF + f];
    red[w][f] = acc;
    __syncthreads();
    if (w == 0)
        pooled[g * LDIM + layerOff + f] =
            scale[f] * (red[0][f] + red[1][f] + red[2][f] + red[3][f])
            + (float)(e - s) * shift[f];
}

// ---------------------------------------------------------------------------
__global__ __launch_bounds__(192) void proj_kernel(
    const float* __restrict__ in,
    const float* __restrict__ W,
    const float* __restrict__ b,
    float* __restrict__ out,
    int do_relu)
{
    __shared__ float rowS[LDIM];
    int r = blockIdx.x;
    int c = threadIdx.x;
    rowS[c] = in[r * LDIM + c];
    __syncthreads();
    float acc = b[c];
    #pragma unroll 4
    for (int k = 0; k < LDIM; ++k) acc += rowS[k] * W[k * LDIM + c];
    out[r * LDIM + c] = do_relu ? fmaxf(acc, 0.0f) : acc;
}

// ---------------------------------------------------------------------------
extern "C" void kernel_launch(void* const* d_in, const int* in_sizes, int n_in,
                              void* d_out, int out_size, void* d_ws, size_t ws_size,
                              hipStream_t stream)
{
    const float* x        = (const float*)d_in[0];
    const int*   ei       = (const int*)d_in[1];
    const int*   batch    = (const int*)d_in[2];
    const float* W1       = (const float*)d_in[3];
    const float* b1       = (const float*)d_in[4];
    const float* W2       = (const float*)d_in[5];
    const float* b2       = (const float*)d_in[6];
    const float* gin_eps  = (const float*)d_in[7];
    const float* gin_bias = (const float*)d_in[8];
    const float* gamma    = (const float*)d_in[9];
    const float* beta     = (const float*)d_in[10];
    const float* Wp1      = (const float*)d_in[11];
    const float* bp1      = (const float*)d_in[12];
    const float* Wp2      = (const float*)d_in[13];
    const float* bp2      = (const float*)d_in[14];
    float* out = (float*)d_out;

    // workspace layout
    float* bufA = (float*)d_ws;                             // N*64 (z3 even layers)
    float* bufB = bufA + (size_t)N_NODES * DF;              // N*64 (z3 odd layers)
    float* pooled = bufB + (size_t)N_NODES * DF;            // NGRAPH*LDIM
    float* hidden = pooled + (size_t)NGRAPH * LDIM;         // NGRAPH*LDIM
    float* scale = hidden + (size_t)NGRAPH * LDIM;          // 64
    float* shift = scale + 64;                              // 64
    float* idsc = shift + 64;                               // 64 (1.0)
    float* idsh = idsc + 64;                                // 64 (0.0)
    float* part_s = idsh + 64;                              // 64*NWT
    float* part_q = part_s + (size_t)64 * NWT;              // 64*NWT
    int* gstart = (int*)(part_q + (size_t)64 * NWT);        // NGRAPH+1
    int* deg  = gstart + NGRAPH + 1;                        // N
    int* off  = deg + N_NODES;                              // N+1
    int* colS = off + N_NODES + 1;                          // COLS_CAP
    int* cur  = colS + COLS_CAP;                            // NBUCK
    int* bpad = cur + NBUCK;                                // NBUCK
    int* bbase = bpad + NBUCK;                              // NBUCK
    unsigned* bucketData = (unsigned*)(bbase + NBUCK);      // NBUCK*BCAP
    short* Wpk = (short*)(bucketData + (size_t)NBUCK * BCAP); // 6*4096 bf16

    // ---- bucketed CSR build + graph segments + weight pack ----
    hipMemsetAsync(cur, 0, NBUCK * sizeof(int), stream);
    bucket_scatter_kernel<<<(N_EDGES + 255) / 256, 256, 0, stream>>>(
        ei, cur, bucketData);
    bucket_count_kernel<<<NBUCK, 256, 0, stream>>>(bucketData, cur, deg, bpad);
    bucket_scan_kernel<<<1, 1024, 0, stream>>>(bpad, bbase);
    bucket_emit_kernel<<<NBUCK, 256, 0, stream>>>(bucketData, cur, bbase,
                                                  off, colS);
    gstart_kernel<<<3, 256, 0, stream>>>(batch, gstart);
    init_id_kernel<<<1, 64, 0, stream>>>(idsc, idsh);
    pack_w_kernel<<<6, 256, 0, stream>>>(W1, W2, Wpk);

    const float* zprev = x;
    const float* sc_in = idsc;
    const float* sh_in = idsh;
    float* zbuf[2] = {bufA, bufB};
    for (int l = 0; l < 3; ++l) {
        float* zcur = zbuf[l & 1];
        gin_layer_kernel<<<GIN_GRID, 256, 0, stream>>>(
            zprev, sc_in, sh_in, off, deg, colS, zcur,
            Wpk + (size_t)l * 8192,
            b1 + l * 64, b2 + l * 64, gin_eps + l, gin_bias + l * 64,
            part_s, part_q);

        stat_reduce_kernel<<<64, 256, 0, stream>>>(
            part_s, part_q, gamma + l * 64, beta + l * 64, scale, shift);

        pool_kernel<<<NGRAPH, 256, 0, stream>>>(
            zcur, scale, shift, gstart, pooled, l * 64);

        zprev = zcur;
        sc_in = scale;
        sh_in = shift;
    }

    proj_kernel<<<NGRAPH, LDIM, 0, stream>>>(pooled, Wp1, bp1, hidden, 1);
    proj_kernel<<<NGRAPH, LDIM, 0, stream>>>(hidden, Wp2, bp2, out, 0);
}

// Round 10
// 294.178 us; speedup vs baseline: 1.5862x; 1.5862x over previous
//
#include <hip/hip_runtime.h>

#define N_NODES 100000
#define N_EDGES 800000
#define DF 64
#define NGRAPH 512
#define LDIM 192   // L * D
#define BN_EPS 1e-5
#define NTILES 6250      // N_NODES / 16
#define GIN_GRID 1563    // ceil(NTILES / 4 waves)
#define NWT (GIN_GRID * 4)   // partial-stat slots (one per wave)
#define COLS_CAP 2600000     // sum of padded degrees < 2.4M
#define NBUCK 782            // ceil(N_NODES / 128)
#define BCAP 2048            // max edges per bucket (avg 1023)
#define NBLK 128             // counting-sort blocks
#define CHUNK 6250           // N_EDGES / NBLK

typedef __attribute__((ext_vector_type(8))) short bf16x8;
typedef __attribute__((ext_vector_type(4))) float f32x4;

__device__ inline short f2bf(float x) {
    union { float f; unsigned u; } v; v.f = x;
    unsigned r = v.u + 0x7fff + ((v.u >> 16) & 1);   // RNE
    return (short)(r >> 16);
}

__device__ inline int pdeg_of(int d) {   // pad to multiple of 16, min 16
    int p = (d + 15) & ~15;
    return p < 16 ? 16 : p;
}

// ---------------------------------------------------------------------------
// Counting-sort CSR build (no global atomics).
// bucket = row >> 7 (128 rows per bucket).
// ---------------------------------------------------------------------------
__global__ __launch_bounds__(256) void blk_hist_kernel(
    const int* __restrict__ ei, int* __restrict__ hist)
{
    __shared__ int hh[NBUCK];
    int blk = blockIdx.x, tid = threadIdx.x;
    for (int i = tid; i < NBUCK; i += 256) hh[i] = 0;
    __syncthreads();
    int start = blk * CHUNK, end = min(start + CHUNK, N_EDGES);
    for (int e = start + tid; e < end; e += 256)
        atomicAdd(&hh[ei[e] >> 7], 1);
    __syncthreads();
    for (int i = tid; i < NBUCK; i += 256) hist[blk * NBUCK + i] = hh[i];
}

__global__ __launch_bounds__(NBLK) void blk_scan_kernel(
    const int* __restrict__ hist, int* __restrict__ pos, int* __restrict__ cnt)
{
    __shared__ int buf[NBLK];
    int k = blockIdx.x, b = threadIdx.x;
    int v = hist[b * NBUCK + k];
    buf[b] = v;
    __syncthreads();
    for (int o = 1; o < NBLK; o <<= 1) {
        int t = (b >= o) ? buf[b - o] : 0;
        __syncthreads();
        buf[b] += t;
        __syncthreads();
    }
    pos[b * NBUCK + k] = buf[b] - v;
    if (b == NBLK - 1) cnt[k] = buf[b];
}

__global__ __launch_bounds__(256) void place_kernel(
    const int* __restrict__ ei, const int* __restrict__ pos,
    unsigned* __restrict__ bucketData)
{
    __shared__ int cursor[NBUCK];
    int blk = blockIdx.x, tid = threadIdx.x;
    for (int i = tid; i < NBUCK; i += 256) cursor[i] = pos[blk * NBUCK + i];
    __syncthreads();
    int start = blk * CHUNK, end = min(start + CHUNK, N_EDGES);
    for (int e = start + tid; e < end; e += 256) {
        int r = ei[e];
        int c = ei[N_EDGES + e];
        int k = r >> 7;
        int p = atomicAdd(&cursor[k], 1);   // LDS atomic, block-local
        bucketData[(size_t)k * BCAP + p] = ((unsigned)(r & 127) << 17) | (unsigned)c;
    }
}

__global__ __launch_bounds__(256) void bucket_count_kernel(
    const unsigned* __restrict__ bucketData, const int* __restrict__ cnt,
    int* __restrict__ deg, int* __restrict__ bpad)
{
    __shared__ int rc[128];
    __shared__ int red[4];
    int b = blockIdx.x, tid = threadIdx.x;
    int rowbase = b << 7;
    int nrows = min(128, N_NODES - rowbase);
    int cntb = cnt[b];
    if (tid < 128) rc[tid] = 0;
    __syncthreads();
    for (int e = tid; e < cntb; e += 256)
        atomicAdd(&rc[bucketData[(size_t)b * BCAP + e] >> 17], 1);
    __syncthreads();
    int v = 0;
    if (tid < nrows) {
        int d = rc[tid];
        deg[rowbase + tid] = d;
        v = pdeg_of(d);
    }
    #pragma unroll
    for (int o = 32; o > 0; o >>= 1) v += __shfl_down(v, o, 64);
    if ((tid & 63) == 0) red[tid >> 6] = v;
    __syncthreads();
    if (tid == 0) bpad[b] = red[0] + red[1] + red[2] + red[3];
}

__global__ __launch_bounds__(1024) void bucket_scan_kernel(
    const int* __restrict__ bpad, int* __restrict__ bbase)
{
    __shared__ int buf[1024];
    int tid = threadIdx.x;
    int own = (tid < NBUCK) ? bpad[tid] : 0;
    buf[tid] = own;
    __syncthreads();
    for (int o = 1; o < 1024; o <<= 1) {
        int t = (tid >= o) ? buf[tid - o] : 0;
        __syncthreads();
        buf[tid] += t;
        __syncthreads();
    }
    if (tid < NBUCK) bbase[tid] = buf[tid] - own;
}

__global__ __launch_bounds__(256) void bucket_emit_kernel(
    const unsigned* __restrict__ bucketData, const int* __restrict__ cnt,
    const int* __restrict__ bbase,
    int* __restrict__ off, int* __restrict__ colS)
{
    __shared__ int rc[128], rstart[128], rcur[128], sbuf[128];
    __shared__ int region[4096];
    int b = blockIdx.x, tid = threadIdx.x;
    int rowbase = b << 7;
    int nrows = min(128, N_NODES - rowbase);
    int cntb = cnt[b];
    int base = bbase[b];
    if (tid < 128) rc[tid] = 0;
    __syncthreads();
    for (int e = tid; e < cntb; e += 256)
        atomicAdd(&rc[bucketData[(size_t)b * BCAP + e] >> 17], 1);
    __syncthreads();
    int pd = (tid < nrows) ? pdeg_of(rc[tid]) : 0;
    if (tid < 128) sbuf[tid] = pd;
    __syncthreads();
    for (int o = 1; o < 128; o <<= 1) {
        int t = 0;
        if (tid < 128 && tid >= o) t = sbuf[tid - o];
        __syncthreads();
        if (tid < 128) sbuf[tid] += t;
        __syncthreads();
    }
    if (tid < 128) { rstart[tid] = sbuf[tid] - pd; rcur[tid] = sbuf[tid] - pd; }
    __syncthreads();
    int total = sbuf[127];
    // place real edges
    for (int e = tid; e < cntb; e += 256) {
        unsigned p = bucketData[(size_t)b * BCAP + e];
        int lr = p >> 17;
        int c = p & 0x1FFFF;
        int pos = atomicAdd(&rcur[lr], 1);
        region[pos] = c * DF;
    }
    __syncthreads();
    // pads point at the node's own row (corrected algebraically in gather)
    for (int i = tid; i < nrows; i += 256) {
        int st = rstart[i] + rc[i];
        int en = rstart[i] + pdeg_of(rc[i]);
        int sent = (rowbase + i) * DF;
        for (int j = st; j < en; ++j) region[j] = sent;
    }
    __syncthreads();
    for (int k = tid; k < total; k += 256) colS[base + k] = region[k];
    if (tid < nrows) off[rowbase + tid] = base + rstart[tid];
    if (b == NBUCK - 1 && tid == 0) off[N_NODES] = base + total;
}

// ---------------------------------------------------------------------------
__global__ __launch_bounds__(256) void gstart_kernel(
    const int* __restrict__ batch, int* __restrict__ gstart)
{
    int g = blockIdx.x * 256 + threadIdx.x;
    if (g > NGRAPH) return;
    if (g == NGRAPH) { gstart[g] = N_NODES; return; }
    int lo = 0, hi = N_NODES;
    while (lo < hi) {
        int mid = (lo + hi) >> 1;
        if (batch[mid] < g) lo = mid + 1; else hi = mid;
    }
    gstart[g] = lo;
}

__global__ void init_id_kernel(float* __restrict__ idsc, float* __restrict__ idsh)
{
    int f = threadIdx.x;
    idsc[f] = 1.0f;
    idsh[f] = 0.0f;
}

// ---------------------------------------------------------------------------
// Pack W (fp32 [64][64], z@W) into MFMA B-fragment order, bf16.
// ---------------------------------------------------------------------------
__global__ __launch_bounds__(256) void pack_w_kernel(
    const float* __restrict__ W1, const float* __restrict__ W2,
    short* __restrict__ Wpk)
{
    int u = blockIdx.x;            // 0..5 = layer*2 + gemm
    int layer = u >> 1, gm = u & 1;
    const float* W = (gm ? W2 : W1) + layer * 4096;
    short* dst = Wpk + u * 4096;
    for (int idx = threadIdx.x; idx < 4096; idx += 256) {
        int i = idx & 7;
        int l = (idx >> 3) & 63;
        int rest = idx >> 9;       // nt*2+kt
        int kt = rest & 1, nt = rest >> 1;
        int k = kt * 32 + (l >> 4) * 8 + i;
        int n = nt * 16 + (l & 15);
        dst[idx] = f2bf(W[k * 64 + n]);
    }
}

// ---------------------------------------------------------------------------
// Fused GIN layer (MFMA). One 16-node tile per wave. Branchless padded
// gather with scalar (SALU) addressing; prev-layer BN folded in:
//   z = sc*((1+eps-npad)*zp_n + sum_all) + (1+eps+deg)*sh
// ---------------------------------------------------------------------------
__global__ __launch_bounds__(256) void gin_layer_kernel(
    const float* __restrict__ zp,       // prev z3 (or x for layer 0)
    const float* __restrict__ sc_in,    // prev BN scale (or 1.0)
    const float* __restrict__ sh_in,    // prev BN shift (or 0.0)
    const int* __restrict__ off,        // padded CSR offsets
    const int* __restrict__ deg,        // real degrees
    const int* __restrict__ colS,       // element offsets (c*64), padded
    float* __restrict__ zout,
    const short* __restrict__ Wpk,      // this layer: [2][4096]
    const float* __restrict__ b1,
    const float* __restrict__ b2,
    const float* __restrict__ gin_eps,
    const float* __restrict__ gin_bias,
    float* __restrict__ part_s,         // [64][NWT]
    float* __restrict__ part_q)
{
    __shared__ __align__(16) short Wp1s[4096];
    __shared__ __align__(16) short Wp2s[4096];
    __shared__ __align__(16) short zs[4][16 * 72];   // z, then z1 (wave-private)

    int tid = threadIdx.x;
    {   // stage packed weights (16 KB), once per block
        const short4* s1 = (const short4*)Wpk;
        const short4* s2 = (const short4*)(Wpk + 4096);
        short4* d1 = (short4*)Wp1s;
        short4* d2 = (short4*)Wp2s;
        for (int i = tid; i < 1024; i += 256) { d1[i] = s1[i]; d2[i] = s2[i]; }
    }

    int w = tid >> 6, l = tid & 63;
    int lr = l & 15;    // A-row / B-col / D-col low index
    int lk = l >> 4;    // k-group / D-row group
    float epsf = 1.0f + gin_eps[0];
    float scf = sc_in[l], shf = sh_in[l];
    float b1f[4], b2f[4], gbf[4];
    #pragma unroll
    for (int nt = 0; nt < 4; ++nt) {
        b1f[nt] = b1[nt * 16 + lr];
        b2f[nt] = b2[nt * 16 + lr];
        gbf[nt] = gin_bias[nt * 16 + lr];
    }
    float ssum[4] = {0, 0, 0, 0}, sq[4] = {0, 0, 0, 0};
    short* zw = zs[w];
    __syncthreads();

    int t = blockIdx.x * 4 + w;
    bool active = t < NTILES;
    int n0 = t * 16;

    if (active) {
        // ---- gather: 2 nodes in flight (32 loads), branchless first batch --
        #pragma unroll 1
        for (int mp = 0; mp < 8; ++mp) {
            int nodeA = n0 + (mp << 1);
            int nodeB = nodeA + 1;
            int sA = __builtin_amdgcn_readfirstlane(off[nodeA]);
            int eA = __builtin_amdgcn_readfirstlane(off[nodeA + 1]);
            int dA = __builtin_amdgcn_readfirstlane(deg[nodeA]);
            int sB = __builtin_amdgcn_readfirstlane(off[nodeB]);
            int eB = __builtin_amdgcn_readfirstlane(off[nodeB + 1]);
            int dB = __builtin_amdgcn_readfirstlane(deg[nodeB]);
            float hnA = zp[nodeA * DF + l];
            float hnB = zp[nodeB * DF + l];
            float vA[16], vB[16];
            #pragma unroll
            for (int j = 0; j < 16; ++j) {
                int co = __builtin_amdgcn_readfirstlane(colS[sA + j]);
                vA[j] = zp[co + l];
            }
            #pragma unroll
            for (int j = 0; j < 16; ++j) {
                int co = __builtin_amdgcn_readfirstlane(colS[sB + j]);
                vB[j] = zp[co + l];
            }
            float aA0 = (vA[0] + vA[1]) + (vA[2] + vA[3]);
            float aA1 = (vA[4] + vA[5]) + (vA[6] + vA[7]);
            float aA2 = (vA[8] + vA[9]) + (vA[10] + vA[11]);
            float aA3 = (vA[12] + vA[13]) + (vA[14] + vA[15]);
            float accA = (aA0 + aA1) + (aA2 + aA3);
            float aB0 = (vB[0] + vB[1]) + (vB[2] + vB[3]);
            float aB1 = (vB[4] + vB[5]) + (vB[6] + vB[7]);
            float aB2 = (vB[8] + vB[9]) + (vB[10] + vB[11]);
            float aB3 = (vB[12] + vB[13]) + (vB[14] + vB[15]);
            float accB = (aB0 + aB1) + (aB2 + aB3);
            // rare remainder (deg > 16): ~0.4% of nodes
            for (int i = sA + 16; i < eA; i += 16) {
                #pragma unroll
                for (int j = 0; j < 16; ++j) {
                    int co = __builtin_amdgcn_readfirstlane(colS[i + j]);
                    accA += zp[co + l];
                }
            }
            for (int i = sB + 16; i < eB; i += 16) {
                #pragma unroll
                for (int j = 0; j < 16; ++j) {
                    int co = __builtin_amdgcn_readfirstlane(colS[i + j]);
                    accB += zp[co + l];
                }
            }
            float npA = (float)(eA - sA - dA);
            float npB = (float)(eB - sB - dB);
            float zfA = scf * ((epsf - npA) * hnA + accA) + (epsf + (float)dA) * shf;
            float zfB = scf * ((epsf - npB) * hnB + accB) + (epsf + (float)dB) * shf;
            zw[(mp * 2) * 72 + l] = f2bf(zfA);
            zw[(mp * 2 + 1) * 72 + l] = f2bf(zfB);
        }

        // ---- GEMM1: z1 = relu(z @ W1 + b1)  (z1 overwrites z rows) ----
        {
            bf16x8 a0 = *(const bf16x8*)&zw[lr * 72 + lk * 8];
            bf16x8 a1 = *(const bf16x8*)&zw[lr * 72 + 32 + lk * 8];
            #pragma unroll
            for (int nt = 0; nt < 4; ++nt) {
                f32x4 acc = {0.f, 0.f, 0.f, 0.f};
                bf16x8 bb0 = *(const bf16x8*)&Wp1s[((nt * 2 + 0) * 64 + l) * 8];
                bf16x8 bb1 = *(const bf16x8*)&Wp1s[((nt * 2 + 1) * 64 + l) * 8];
                acc = __builtin_amdgcn_mfma_f32_16x16x32_bf16(a0, bb0, acc, 0, 0, 0);
                acc = __builtin_amdgcn_mfma_f32_16x16x32_bf16(a1, bb1, acc, 0, 0, 0);
                #pragma unroll
                for (int r = 0; r < 4; ++r) {
                    float v = fmaxf(acc[r] + b1f[nt], 0.0f);
                    zw[(lk * 4 + r) * 72 + nt * 16 + lr] = f2bf(v);
                }
            }
        }

        // ---- GEMM2: z3 = relu(relu(z1 @ W2 + b2) + gin_bias) ----
        {
            bf16x8 a0 = *(const bf16x8*)&zw[lr * 72 + lk * 8];
            bf16x8 a1 = *(const bf16x8*)&zw[lr * 72 + 32 + lk * 8];
            #pragma unroll
            for (int nt = 0; nt < 4; ++nt) {
                f32x4 acc = {0.f, 0.f, 0.f, 0.f};
                bf16x8 bb0 = *(const bf16x8*)&Wp2s[((nt * 2 + 0) * 64 + l) * 8];
                bf16x8 bb1 = *(const bf16x8*)&Wp2s[((nt * 2 + 1) * 64 + l) * 8];
                acc = __builtin_amdgcn_mfma_f32_16x16x32_bf16(a0, bb0, acc, 0, 0, 0);
                acc = __builtin_amdgcn_mfma_f32_16x16x32_bf16(a1, bb1, acc, 0, 0, 0);
                #pragma unroll
                for (int r = 0; r < 4; ++r) {
                    float v = fmaxf(fmaxf(acc[r] + b2f[nt], 0.0f) + gbf[nt], 0.0f);
                    zout[(n0 + lk * 4 + r) * DF + nt * 16 + lr] = v;
                    ssum[nt] += v;
                    sq[nt] += v * v;
                }
            }
        }
    }

    // ---- per-wave BN partials (all waves write; zeros if inactive) ----
    #pragma unroll
    for (int nt = 0; nt < 4; ++nt) {
        float sv = ssum[nt], qv = sq[nt];
        sv += __shfl_xor(sv, 16, 64); sv += __shfl_xor(sv, 32, 64);
        qv += __shfl_xor(qv, 16, 64); qv += __shfl_xor(qv, 32, 64);
        if (l < 16) {
            part_s[(nt * 16 + l) * NWT + t] = sv;
            part_q[(nt * 16 + l) * NWT + t] = qv;
        }
    }
}

// ---------------------------------------------------------------------------
// Reduce per-wave partials -> BN scale/shift (one block per feature)
// ---------------------------------------------------------------------------
__global__ __launch_bounds__(256) void stat_reduce_kernel(
    const float* __restrict__ part_s, const float* __restrict__ part_q,
    const float* __restrict__ gamma, const float* __restrict__ beta,
    float* __restrict__ scale, float* __restrict__ shift)
{
    __shared__ double rs[4], rq[4];
    int f = blockIdx.x, tid = threadIdx.x;
    double s = 0.0, q = 0.0;
    for (int j = tid; j < NWT; j += 256) {
        s += (double)part_s[f * NWT + j];
        q += (double)part_q[f * NWT + j];
    }
    for (int o = 32; o > 0; o >>= 1) {
        s += __shfl_down(s, o, 64);
        q += __shfl_down(q, o, 64);
    }
    if ((tid & 63) == 0) { rs[tid >> 6] = s; rq[tid >> 6] = q; }
    __syncthreads();
    if (tid == 0) {
        double st = rs[0] + rs[1] + rs[2] + rs[3];
        double qt = rq[0] + rq[1] + rq[2] + rq[3];
        double mean = st / N_NODES;
        double var = qt / N_NODES - mean * mean;
        double inv = (double)gamma[f] / sqrt(var + BN_EPS);
        scale[f] = (float)inv;
        shift[f] = (float)((double)beta[f] - mean * inv);
    }
}

// ---------------------------------------------------------------------------
// Pool-only: pooled[g] = sc * sum_{nodes in g} z3 + cnt(g) * sh
// ---------------------------------------------------------------------------
__global__ __launch_bounds__(256) void pool_kernel(
    const float* __restrict__ z,
    const float* __restrict__ scale,
    const float* __restrict__ shift,
    const int* __restrict__ gstart,
    float* __restrict__ pooled,
    int layerOff)
{
    __shared__ float red[4][64];
    int g = blockIdx.x;
    int tid = threadIdx.x;
    int w = tid >> 6, f = tid & 63;

    int s = gstart[g], e = gstart[g + 1];
    float acc = 0.0f;
    for (int node = s + w; node < e; node += 4)
        acc += z[node * DF + f];
    red[w][f] = acc;
    __syncthreads();
    if (w == 0)
        pooled[g * LDIM + layerOff + f] =
            scale[f] * (red[0][f] + red[1][f] + red[2][f] + red[3][f])
            + (float)(e - s) * shift[f];
}

// ---------------------------------------------------------------------------
__global__ __launch_bounds__(192) void proj_kernel(
    const float* __restrict__ in,
    const float* __restrict__ W,
    const float* __restrict__ b,
    float* __restrict__ out,
    int do_relu)
{
    __shared__ float rowS[LDIM];
    int r = blockIdx.x;
    int c = threadIdx.x;
    rowS[c] = in[r * LDIM + c];
    __syncthreads();
    float acc = b[c];
    #pragma unroll 4
    for (int k = 0; k < LDIM; ++k) acc += rowS[k] * W[k * LDIM + c];
    out[r * LDIM + c] = do_relu ? fmaxf(acc, 0.0f) : acc;
}

// ---------------------------------------------------------------------------
extern "C" void kernel_launch(void* const* d_in, const int* in_sizes, int n_in,
                              void* d_out, int out_size, void* d_ws, size_t ws_size,
                              hipStream_t stream)
{
    const float* x        = (const float*)d_in[0];
    const int*   ei       = (const int*)d_in[1];
    const int*   batch    = (const int*)d_in[2];
    const float* W1       = (const float*)d_in[3];
    const float* b1       = (const float*)d_in[4];
    const float* W2       = (const float*)d_in[5];
    const float* b2       = (const float*)d_in[6];
    const float* gin_eps  = (const float*)d_in[7];
    const float* gin_bias = (const float*)d_in[8];
    const float* gamma    = (const float*)d_in[9];
    const float* beta     = (const float*)d_in[10];
    const float* Wp1      = (const float*)d_in[11];
    const float* bp1      = (const float*)d_in[12];
    const float* Wp2      = (const float*)d_in[13];
    const float* bp2      = (const float*)d_in[14];
    float* out = (float*)d_out;

    // workspace layout
    float* bufA = (float*)d_ws;                             // N*64 (z3 even layers)
    float* bufB = bufA + (size_t)N_NODES * DF;              // N*64 (z3 odd layers)
    float* pooled = bufB + (size_t)N_NODES * DF;            // NGRAPH*LDIM
    float* hidden = pooled + (size_t)NGRAPH * LDIM;         // NGRAPH*LDIM
    float* scale = hidden + (size_t)NGRAPH * LDIM;          // 64
    float* shift = scale + 64;                              // 64
    float* idsc = shift + 64;                               // 64 (1.0)
    float* idsh = idsc + 64;                                // 64 (0.0)
    float* part_s = idsh + 64;                              // 64*NWT
    float* part_q = part_s + (size_t)64 * NWT;              // 64*NWT
    int* gstart = (int*)(part_q + (size_t)64 * NWT);        // NGRAPH+1
    int* deg  = gstart + NGRAPH + 1;                        // N
    int* off  = deg + N_NODES;                              // N+1
    int* colS = off + N_NODES + 1;                          // COLS_CAP
    int* hist = colS + COLS_CAP;                            // NBLK*NBUCK
    int* pos  = hist + NBLK * NBUCK;                        // NBLK*NBUCK
    int* cnt  = pos + NBLK * NBUCK;                         // NBUCK
    int* bpad = cnt + NBUCK;                                // NBUCK
    int* bbase = bpad + NBUCK;                              // NBUCK
    unsigned* bucketData = (unsigned*)(bbase + NBUCK);      // NBUCK*BCAP
    short* Wpk = (short*)(bucketData + (size_t)NBUCK * BCAP); // 6*4096 bf16

    // ---- counting-sort CSR build + graph segments + weight pack ----
    blk_hist_kernel<<<NBLK, 256, 0, stream>>>(ei, hist);
    blk_scan_kernel<<<NBUCK, NBLK, 0, stream>>>(hist, pos, cnt);
    place_kernel<<<NBLK, 256, 0, stream>>>(ei, pos, bucketData);
    bucket_count_kernel<<<NBUCK, 256, 0, stream>>>(bucketData, cnt, deg, bpad);
    bucket_scan_kernel<<<1, 1024, 0, stream>>>(bpad, bbase);
    bucket_emit_kernel<<<NBUCK, 256, 0, stream>>>(bucketData, cnt, bbase,
                                                  off, colS);
    gstart_kernel<<<3, 256, 0, stream>>>(batch, gstart);
    init_id_kernel<<<1, 64, 0, stream>>>(idsc, idsh);
    pack_w_kernel<<<6, 256, 0, stream>>>(W1, W2, Wpk);

    const float* zprev = x;
    const float* sc_in = idsc;
    const float* sh_in = idsh;
    float* zbuf[2] = {bufA, bufB};
    for (int l = 0; l < 3; ++l) {
        float* zcur = zbuf[l & 1];
        gin_layer_kernel<<<GIN_GRID, 256, 0, stream>>>(
            zprev, sc_in, sh_in, off, deg, colS, zcur,
            Wpk + (size_t)l * 8192,
            b1 + l * 64, b2 + l * 64, gin_eps + l, gin_bias + l * 64,
            part_s, part_q);

        stat_reduce_kernel<<<64, 256, 0, stream>>>(
            part_s, part_q, gamma + l * 64, beta + l * 64, scale, shift);

        pool_kernel<<<NGRAPH, 256, 0, stream>>>(
            zcur, scale, shift, gstart, pooled, l * 64);

        zprev = zcur;
        sc_in = scale;
        sh_in = shift;
    }

    proj_kernel<<<NGRAPH, LDIM, 0, stream>>>(pooled, Wp1, bp1, hidden, 1);
    proj_kernel<<<NGRAPH, LDIM, 0, stream>>>(hidden, Wp2, bp2, out, 0);
}

// Round 11
// 277.951 us; speedup vs baseline: 1.6788x; 1.0584x over previous
//
#include <hip/hip_runtime.h>

#define N_NODES 100000
#define N_EDGES 800000
#define DF 64
#define NGRAPH 512
#define LDIM 192   // L * D
#define BN_EPS 1e-5
#define NTILES 6250      // N_NODES / 16
#define GIN_GRID 1563    // ceil(NTILES / 4 waves)
#define NWT (GIN_GRID * 4)   // partial-stat slots (one per wave)
#define COLS_CAP 2600000     // sum of padded degrees < 2.4M
#define NBUCK 782            // ceil(N_NODES / 128)
#define BCAP 2048            // max edges per bucket (avg 1023)
#define NBLK 128             // counting-sort blocks
#define CHUNK 6250           // N_EDGES / NBLK

typedef __attribute__((ext_vector_type(8))) short bf16x8;
typedef __attribute__((ext_vector_type(4))) float f32x4;

__device__ inline short f2bf(float x) {
    union { float f; unsigned u; } v; v.f = x;
    unsigned r = v.u + 0x7fff + ((v.u >> 16) & 1);   // RNE
    return (short)(r >> 16);
}

__device__ inline float bf2f(unsigned short u) {
    union { unsigned u; float f; } v;
    v.u = ((unsigned)u) << 16;
    return v.f;
}

__device__ inline int pdeg_of(int d) {   // pad to multiple of 16, min 16
    int p = (d + 15) & ~15;
    return p < 16 ? 16 : p;
}

// ---------------------------------------------------------------------------
// Counting-sort CSR build (no global atomics). bucket = row >> 7.
// ---------------------------------------------------------------------------
__global__ __launch_bounds__(256) void blk_hist_kernel(
    const int* __restrict__ ei, int* __restrict__ hist)
{
    __shared__ int hh[NBUCK];
    int blk = blockIdx.x, tid = threadIdx.x;
    for (int i = tid; i < NBUCK; i += 256) hh[i] = 0;
    __syncthreads();
    int start = blk * CHUNK, end = min(start + CHUNK, N_EDGES);
    for (int e = start + tid; e < end; e += 256)
        atomicAdd(&hh[ei[e] >> 7], 1);
    __syncthreads();
    for (int i = tid; i < NBUCK; i += 256) hist[blk * NBUCK + i] = hh[i];
}

__global__ __launch_bounds__(NBLK) void blk_scan_kernel(
    const int* __restrict__ hist, int* __restrict__ pos, int* __restrict__ cnt)
{
    __shared__ int buf[NBLK];
    int k = blockIdx.x, b = threadIdx.x;
    int v = hist[b * NBUCK + k];
    buf[b] = v;
    __syncthreads();
    for (int o = 1; o < NBLK; o <<= 1) {
        int t = (b >= o) ? buf[b - o] : 0;
        __syncthreads();
        buf[b] += t;
        __syncthreads();
    }
    pos[b * NBUCK + k] = buf[b] - v;
    if (b == NBLK - 1) cnt[k] = buf[b];
}

__global__ __launch_bounds__(256) void place_kernel(
    const int* __restrict__ ei, const int* __restrict__ pos,
    unsigned* __restrict__ bucketData)
{
    __shared__ int cursor[NBUCK];
    int blk = blockIdx.x, tid = threadIdx.x;
    for (int i = tid; i < NBUCK; i += 256) cursor[i] = pos[blk * NBUCK + i];
    __syncthreads();
    int start = blk * CHUNK, end = min(start + CHUNK, N_EDGES);
    for (int e = start + tid; e < end; e += 256) {
        int r = ei[e];
        int c = ei[N_EDGES + e];
        int k = r >> 7;
        int p = atomicAdd(&cursor[k], 1);   // LDS atomic, block-local
        bucketData[(size_t)k * BCAP + p] = ((unsigned)(r & 127) << 17) | (unsigned)c;
    }
}

__global__ __launch_bounds__(256) void bucket_count_kernel(
    const unsigned* __restrict__ bucketData, const int* __restrict__ cnt,
    int* __restrict__ deg, int* __restrict__ bpad)
{
    __shared__ int rc[128];
    __shared__ int red[4];
    int b = blockIdx.x, tid = threadIdx.x;
    int rowbase = b << 7;
    int nrows = min(128, N_NODES - rowbase);
    int cntb = cnt[b];
    if (tid < 128) rc[tid] = 0;
    __syncthreads();
    for (int e = tid; e < cntb; e += 256)
        atomicAdd(&rc[bucketData[(size_t)b * BCAP + e] >> 17], 1);
    __syncthreads();
    int v = 0;
    if (tid < nrows) {
        int d = rc[tid];
        deg[rowbase + tid] = d;
        v = pdeg_of(d);
    }
    #pragma unroll
    for (int o = 32; o > 0; o >>= 1) v += __shfl_down(v, o, 64);
    if ((tid & 63) == 0) red[tid >> 6] = v;
    __syncthreads();
    if (tid == 0) bpad[b] = red[0] + red[1] + red[2] + red[3];
}

__global__ __launch_bounds__(1024) void bucket_scan_kernel(
    const int* __restrict__ bpad, int* __restrict__ bbase)
{
    __shared__ int buf[1024];
    int tid = threadIdx.x;
    int own = (tid < NBUCK) ? bpad[tid] : 0;
    buf[tid] = own;
    __syncthreads();
    for (int o = 1; o < 1024; o <<= 1) {
        int t = (tid >= o) ? buf[tid - o] : 0;
        __syncthreads();
        buf[tid] += t;
        __syncthreads();
    }
    if (tid < NBUCK) bbase[tid] = buf[tid] - own;
}

__global__ __launch_bounds__(256) void bucket_emit_kernel(
    const unsigned* __restrict__ bucketData, const int* __restrict__ cnt,
    const int* __restrict__ bbase,
    int* __restrict__ off, int* __restrict__ colS)
{
    __shared__ int rc[128], rstart[128], rcur[128], sbuf[128];
    __shared__ int region[4096];
    int b = blockIdx.x, tid = threadIdx.x;
    int rowbase = b << 7;
    int nrows = min(128, N_NODES - rowbase);
    int cntb = cnt[b];
    int base = bbase[b];
    if (tid < 128) rc[tid] = 0;
    __syncthreads();
    for (int e = tid; e < cntb; e += 256)
        atomicAdd(&rc[bucketData[(size_t)b * BCAP + e] >> 17], 1);
    __syncthreads();
    int pd = (tid < nrows) ? pdeg_of(rc[tid]) : 0;
    if (tid < 128) sbuf[tid] = pd;
    __syncthreads();
    for (int o = 1; o < 128; o <<= 1) {
        int t = 0;
        if (tid < 128 && tid >= o) t = sbuf[tid - o];
        __syncthreads();
        if (tid < 128) sbuf[tid] += t;
        __syncthreads();
    }
    if (tid < 128) { rstart[tid] = sbuf[tid] - pd; rcur[tid] = sbuf[tid] - pd; }
    __syncthreads();
    int total = sbuf[127];
    for (int e = tid; e < cntb; e += 256) {
        unsigned p = bucketData[(size_t)b * BCAP + e];
        int lr = p >> 17;
        int c = p & 0x1FFFF;
        int pos = atomicAdd(&rcur[lr], 1);
        region[pos] = c * DF;
    }
    __syncthreads();
    for (int i = tid; i < nrows; i += 256) {
        int st = rstart[i] + rc[i];
        int en = rstart[i] + pdeg_of(rc[i]);
        int sent = (rowbase + i) * DF;
        for (int j = st; j < en; ++j) region[j] = sent;
    }
    __syncthreads();
    for (int k = tid; k < total; k += 256) colS[base + k] = region[k];
    if (tid < nrows) off[rowbase + tid] = base + rstart[tid];
    if (b == NBUCK - 1 && tid == 0) off[N_NODES] = base + total;
}

// ---------------------------------------------------------------------------
__global__ __launch_bounds__(256) void gstart_kernel(
    const int* __restrict__ batch, int* __restrict__ gstart,
    float* __restrict__ idsc, float* __restrict__ idsh)
{
    int g = blockIdx.x * 256 + threadIdx.x;
    if (g < 64) { idsc[g] = 1.0f; idsh[g] = 0.0f; }
    if (g > NGRAPH) return;
    if (g == NGRAPH) { gstart[g] = N_NODES; return; }
    int lo = 0, hi = N_NODES;
    while (lo < hi) {
        int mid = (lo + hi) >> 1;
        if (batch[mid] < g) lo = mid + 1; else hi = mid;
    }
    gstart[g] = lo;
}

// ---------------------------------------------------------------------------
// Pack W (fp32 [64][64], z@W) into MFMA B-fragment order, bf16.
// ---------------------------------------------------------------------------
__global__ __launch_bounds__(256) void pack_w_kernel(
    const float* __restrict__ W1, const float* __restrict__ W2,
    short* __restrict__ Wpk)
{
    int u = blockIdx.x;            // 0..5 = layer*2 + gemm
    int layer = u >> 1, gm = u & 1;
    const float* W = (gm ? W2 : W1) + layer * 4096;
    short* dst = Wpk + u * 4096;
    for (int idx = threadIdx.x; idx < 4096; idx += 256) {
        int i = idx & 7;
        int l = (idx >> 3) & 63;
        int rest = idx >> 9;       // nt*2+kt
        int kt = rest & 1, nt = rest >> 1;
        int k = kt * 32 + (l >> 4) * 8 + i;
        int n = nt * 16 + (l & 15);
        dst[idx] = f2bf(W[k * 64 + n]);
    }
}

// ---------------------------------------------------------------------------
// Fused GIN layer (MFMA). One 16-node tile per wave. Branchless padded
// gather (SALU addressing); prev-layer BN folded in. BF16IN: zp is bf16
// (layers 1,2); else fp32 (layer 0, x). zout is bf16.
// ---------------------------------------------------------------------------
template <bool BF16IN>
__global__ __launch_bounds__(256) void gin_layer_kernel(
    const void* __restrict__ zp_,
    const float* __restrict__ sc_in,
    const float* __restrict__ sh_in,
    const int* __restrict__ off,
    const int* __restrict__ deg,
    const int* __restrict__ colS,
    unsigned short* __restrict__ zout,  // bf16
    const short* __restrict__ Wpk,
    const float* __restrict__ b1,
    const float* __restrict__ b2,
    const float* __restrict__ gin_eps,
    const float* __restrict__ gin_bias,
    float* __restrict__ part_s,
    float* __restrict__ part_q)
{
    __shared__ __align__(16) short Wp1s[4096];
    __shared__ __align__(16) short Wp2s[4096];
    __shared__ __align__(16) short zs[4][16 * 72];

    const float* zpf = (const float*)zp_;
    const unsigned short* zpb = (const unsigned short*)zp_;

    int tid = threadIdx.x;
    {   // stage packed weights (16 KB), once per block
        const short4* s1 = (const short4*)Wpk;
        const short4* s2 = (const short4*)(Wpk + 4096);
        short4* d1 = (short4*)Wp1s;
        short4* d2 = (short4*)Wp2s;
        for (int i = tid; i < 1024; i += 256) { d1[i] = s1[i]; d2[i] = s2[i]; }
    }

    int w = tid >> 6, l = tid & 63;
    int lr = l & 15;
    int lk = l >> 4;
    float epsf = 1.0f + gin_eps[0];
    float scf = sc_in[l], shf = sh_in[l];
    float b1f[4], b2f[4], gbf[4];
    #pragma unroll
    for (int nt = 0; nt < 4; ++nt) {
        b1f[nt] = b1[nt * 16 + lr];
        b2f[nt] = b2[nt * 16 + lr];
        gbf[nt] = gin_bias[nt * 16 + lr];
    }
    float ssum[4] = {0, 0, 0, 0}, sq[4] = {0, 0, 0, 0};
    short* zw = zs[w];
    __syncthreads();

    int t = blockIdx.x * 4 + w;
    bool active = t < NTILES;
    int n0 = t * 16;

    if (active) {
        #pragma unroll 1
        for (int mp = 0; mp < 8; ++mp) {
            int nodeA = n0 + (mp << 1);
            int nodeB = nodeA + 1;
            int sA = __builtin_amdgcn_readfirstlane(off[nodeA]);
            int eA = __builtin_amdgcn_readfirstlane(off[nodeA + 1]);
            int dA = __builtin_amdgcn_readfirstlane(deg[nodeA]);
            int sB = __builtin_amdgcn_readfirstlane(off[nodeB]);
            int eB = __builtin_amdgcn_readfirstlane(off[nodeB + 1]);
            int dB = __builtin_amdgcn_readfirstlane(deg[nodeB]);
            float hnA, hnB;
            if (BF16IN) { hnA = bf2f(zpb[nodeA * DF + l]); hnB = bf2f(zpb[nodeB * DF + l]); }
            else        { hnA = zpf[nodeA * DF + l];       hnB = zpf[nodeB * DF + l]; }
            float vA[16], vB[16];
            #pragma unroll
            for (int j = 0; j < 16; ++j) {
                int co = __builtin_amdgcn_readfirstlane(colS[sA + j]);
                vA[j] = BF16IN ? bf2f(zpb[co + l]) : zpf[co + l];
            }
            #pragma unroll
            for (int j = 0; j < 16; ++j) {
                int co = __builtin_amdgcn_readfirstlane(colS[sB + j]);
                vB[j] = BF16IN ? bf2f(zpb[co + l]) : zpf[co + l];
            }
            float aA0 = (vA[0] + vA[1]) + (vA[2] + vA[3]);
            float aA1 = (vA[4] + vA[5]) + (vA[6] + vA[7]);
            float aA2 = (vA[8] + vA[9]) + (vA[10] + vA[11]);
            float aA3 = (vA[12] + vA[13]) + (vA[14] + vA[15]);
            float accA = (aA0 + aA1) + (aA2 + aA3);
            float aB0 = (vB[0] + vB[1]) + (vB[2] + vB[3]);
            float aB1 = (vB[4] + vB[5]) + (vB[6] + vB[7]);
            float aB2 = (vB[8] + vB[9]) + (vB[10] + vB[11]);
            float aB3 = (vB[12] + vB[13]) + (vB[14] + vB[15]);
            float accB = (aB0 + aB1) + (aB2 + aB3);
            for (int i = sA + 16; i < eA; i += 16) {
                #pragma unroll
                for (int j = 0; j < 16; ++j) {
                    int co = __builtin_amdgcn_readfirstlane(colS[i + j]);
                    accA += BF16IN ? bf2f(zpb[co + l]) : zpf[co + l];
                }
            }
            for (int i = sB + 16; i < eB; i += 16) {
                #pragma unroll
                for (int j = 0; j < 16; ++j) {
                    int co = __builtin_amdgcn_readfirstlane(colS[i + j]);
                    accB += BF16IN ? bf2f(zpb[co + l]) : zpf[co + l];
                }
            }
            float npA = (float)(eA - sA - dA);
            float npB = (float)(eB - sB - dB);
            float zfA = scf * ((epsf - npA) * hnA + accA) + (epsf + (float)dA) * shf;
            float zfB = scf * ((epsf - npB) * hnB + accB) + (epsf + (float)dB) * shf;
            zw[(mp * 2) * 72 + l] = f2bf(zfA);
            zw[(mp * 2 + 1) * 72 + l] = f2bf(zfB);
        }

        // ---- GEMM1 ----
        {
            bf16x8 a0 = *(const bf16x8*)&zw[lr * 72 + lk * 8];
            bf16x8 a1 = *(const bf16x8*)&zw[lr * 72 + 32 + lk * 8];
            #pragma unroll
            for (int nt = 0; nt < 4; ++nt) {
                f32x4 acc = {0.f, 0.f, 0.f, 0.f};
                bf16x8 bb0 = *(const bf16x8*)&Wp1s[((nt * 2 + 0) * 64 + l) * 8];
                bf16x8 bb1 = *(const bf16x8*)&Wp1s[((nt * 2 + 1) * 64 + l) * 8];
                acc = __builtin_amdgcn_mfma_f32_16x16x32_bf16(a0, bb0, acc, 0, 0, 0);
                acc = __builtin_amdgcn_mfma_f32_16x16x32_bf16(a1, bb1, acc, 0, 0, 0);
                #pragma unroll
                for (int r = 0; r < 4; ++r) {
                    float v = fmaxf(acc[r] + b1f[nt], 0.0f);
                    zw[(lk * 4 + r) * 72 + nt * 16 + lr] = f2bf(v);
                }
            }
        }

        // ---- GEMM2 + epilogue (store bf16, stats on rounded value) ----
        {
            bf16x8 a0 = *(const bf16x8*)&zw[lr * 72 + lk * 8];
            bf16x8 a1 = *(const bf16x8*)&zw[lr * 72 + 32 + lk * 8];
            #pragma unroll
            for (int nt = 0; nt < 4; ++nt) {
                f32x4 acc = {0.f, 0.f, 0.f, 0.f};
                bf16x8 bb0 = *(const bf16x8*)&Wp2s[((nt * 2 + 0) * 64 + l) * 8];
                bf16x8 bb1 = *(const bf16x8*)&Wp2s[((nt * 2 + 1) * 64 + l) * 8];
                acc = __builtin_amdgcn_mfma_f32_16x16x32_bf16(a0, bb0, acc, 0, 0, 0);
                acc = __builtin_amdgcn_mfma_f32_16x16x32_bf16(a1, bb1, acc, 0, 0, 0);
                #pragma unroll
                for (int r = 0; r < 4; ++r) {
                    float v = fmaxf(fmaxf(acc[r] + b2f[nt], 0.0f) + gbf[nt], 0.0f);
                    unsigned short vb = (unsigned short)f2bf(v);
                    zout[(n0 + lk * 4 + r) * DF + nt * 16 + lr] = vb;
                    float vr = bf2f(vb);
                    ssum[nt] += vr;
                    sq[nt] += vr * vr;
                }
            }
        }
    }

    #pragma unroll
    for (int nt = 0; nt < 4; ++nt) {
        float sv = ssum[nt], qv = sq[nt];
        sv += __shfl_xor(sv, 16, 64); sv += __shfl_xor(sv, 32, 64);
        qv += __shfl_xor(qv, 16, 64); qv += __shfl_xor(qv, 32, 64);
        if (l < 16) {
            part_s[(nt * 16 + l) * NWT + t] = sv;
            part_q[(nt * 16 + l) * NWT + t] = qv;
        }
    }
}

// ---------------------------------------------------------------------------
__global__ __launch_bounds__(256) void stat_reduce_kernel(
    const float* __restrict__ part_s, const float* __restrict__ part_q,
    const float* __restrict__ gamma, const float* __restrict__ beta,
    float* __restrict__ scale, float* __restrict__ shift)
{
    __shared__ double rs[4], rq[4];
    int f = blockIdx.x, tid = threadIdx.x;
    double s = 0.0, q = 0.0;
    for (int j = tid; j < NWT; j += 256) {
        s += (double)part_s[f * NWT + j];
        q += (double)part_q[f * NWT + j];
    }
    for (int o = 32; o > 0; o >>= 1) {
        s += __shfl_down(s, o, 64);
        q += __shfl_down(q, o, 64);
    }
    if ((tid & 63) == 0) { rs[tid >> 6] = s; rq[tid >> 6] = q; }
    __syncthreads();
    if (tid == 0) {
        double st = rs[0] + rs[1] + rs[2] + rs[3];
        double qt = rq[0] + rq[1] + rq[2] + rq[3];
        double mean = st / N_NODES;
        double var = qt / N_NODES - mean * mean;
        double inv = (double)gamma[f] / sqrt(var + BN_EPS);
        scale[f] = (float)inv;
        shift[f] = (float)((double)beta[f] - mean * inv);
    }
}

// ---------------------------------------------------------------------------
// Pool-only (bf16 z3): pooled[g] = sc * sum z3 + cnt(g) * sh
// ---------------------------------------------------------------------------
__global__ __launch_bounds__(256) void pool_kernel(
    const unsigned short* __restrict__ z,
    const float* __restrict__ scale,
    const float* __restrict__ shift,
    const int* __restrict__ gstart,
    float* __restrict__ pooled,
    int layerOff)
{
    __shared__ float red[4][64];
    int g = blockIdx.x;
    int tid = threadIdx.x;
    int w = tid >> 6, f = tid & 63;

    int s = gstart[g], e = gstart[g + 1];
    float acc = 0.0f;
    for (int node = s + w; node < e; node += 4)
        acc += bf2f(z[node * DF + f]);
    red[w][f] = acc;
    __syncthreads();
    if (w == 0)
        pooled[g * LDIM + layerOff + f] =
            scale[f] * (red[0][f] + red[1][f] + red[2][f] + red[3][f])
            + (float)(e - s) * shift[f];
}

// ---------------------------------------------------------------------------
// Fused projection head: out = relu(pooled@Wp1+bp1) @ Wp2 + bp2 (row-local)
// ---------------------------------------------------------------------------
__global__ __launch_bounds__(192) void proj_fused_kernel(
    const float* __restrict__ in,
    const float* __restrict__ Wp1, const float* __restrict__ bp1,
    const float* __restrict__ Wp2, const float* __restrict__ bp2,
    float* __restrict__ out)
{
    __shared__ float rowS[LDIM];
    __shared__ float hid[LDIM];
    int r = blockIdx.x;
    int c = threadIdx.x;
    rowS[c] = in[r * LDIM + c];
    __syncthreads();
    float acc = bp1[c];
    #pragma unroll 4
    for (int k = 0; k < LDIM; ++k) acc += rowS[k] * Wp1[k * LDIM + c];
    hid[c] = fmaxf(acc, 0.0f);
    __syncthreads();
    float acc2 = bp2[c];
    #pragma unroll 4
    for (int k = 0; k < LDIM; ++k) acc2 += hid[k] * Wp2[k * LDIM + c];
    out[r * LDIM + c] = acc2;
}

// ---------------------------------------------------------------------------
extern "C" void kernel_launch(void* const* d_in, const int* in_sizes, int n_in,
                              void* d_out, int out_size, void* d_ws, size_t ws_size,
                              hipStream_t stream)
{
    const float* x        = (const float*)d_in[0];
    const int*   ei       = (const int*)d_in[1];
    const int*   batch    = (const int*)d_in[2];
    const float* W1       = (const float*)d_in[3];
    const float* b1       = (const float*)d_in[4];
    const float* W2       = (const float*)d_in[5];
    const float* b2       = (const float*)d_in[6];
    const float* gin_eps  = (const float*)d_in[7];
    const float* gin_bias = (const float*)d_in[8];
    const float* gamma    = (const float*)d_in[9];
    const float* beta     = (const float*)d_in[10];
    const float* Wp1      = (const float*)d_in[11];
    const float* bp1      = (const float*)d_in[12];
    const float* Wp2      = (const float*)d_in[13];
    const float* bp2      = (const float*)d_in[14];
    float* out = (float*)d_out;

    // workspace layout
    unsigned short* zbufA = (unsigned short*)d_ws;          // N*64 bf16
    unsigned short* zbufB = zbufA + (size_t)N_NODES * DF;   // N*64 bf16
    float* pooled = (float*)(zbufB + (size_t)N_NODES * DF); // NGRAPH*LDIM
    float* scale = pooled + (size_t)NGRAPH * LDIM;          // 64
    float* shift = scale + 64;                              // 64
    float* idsc = shift + 64;                               // 64 (1.0)
    float* idsh = idsc + 64;                                // 64 (0.0)
    float* part_s = idsh + 64;                              // 64*NWT
    float* part_q = part_s + (size_t)64 * NWT;              // 64*NWT
    int* gstart = (int*)(part_q + (size_t)64 * NWT);        // NGRAPH+1
    int* deg  = gstart + NGRAPH + 1;                        // N
    int* off  = deg + N_NODES;                              // N+1
    int* colS = off + N_NODES + 1;                          // COLS_CAP
    int* hist = colS + COLS_CAP;                            // NBLK*NBUCK
    int* pos  = hist + NBLK * NBUCK;                        // NBLK*NBUCK
    int* cnt  = pos + NBLK * NBUCK;                         // NBUCK
    int* bpad = cnt + NBUCK;                                // NBUCK
    int* bbase = bpad + NBUCK;                              // NBUCK
    unsigned* bucketData = (unsigned*)(bbase + NBUCK);      // NBUCK*BCAP
    short* Wpk = (short*)(bucketData + (size_t)NBUCK * BCAP); // 6*4096 bf16

    // ---- counting-sort CSR build + graph segments + weight pack ----
    blk_hist_kernel<<<NBLK, 256, 0, stream>>>(ei, hist);
    blk_scan_kernel<<<NBUCK, NBLK, 0, stream>>>(hist, pos, cnt);
    place_kernel<<<NBLK, 256, 0, stream>>>(ei, pos, bucketData);
    bucket_count_kernel<<<NBUCK, 256, 0, stream>>>(bucketData, cnt, deg, bpad);
    bucket_scan_kernel<<<1, 1024, 0, stream>>>(bpad, bbase);
    bucket_emit_kernel<<<NBUCK, 256, 0, stream>>>(bucketData, cnt, bbase,
                                                  off, colS);
    gstart_kernel<<<3, 256, 0, stream>>>(batch, gstart, idsc, idsh);
    pack_w_kernel<<<6, 256, 0, stream>>>(W1, W2, Wpk);

    unsigned short* zbuf[2] = {zbufA, zbufB};
    const void* zprev = (const void*)x;
    const float* sc_in = idsc;
    const float* sh_in = idsh;
    for (int l = 0; l < 3; ++l) {
        unsigned short* zcur = zbuf[l & 1];
        if (l == 0)
            gin_layer_kernel<false><<<GIN_GRID, 256, 0, stream>>>(
                zprev, sc_in, sh_in, off, deg, colS, zcur,
                Wpk + (size_t)l * 8192,
                b1 + l * 64, b2 + l * 64, gin_eps + l, gin_bias + l * 64,
                part_s, part_q);
        else
            gin_layer_kernel<true><<<GIN_GRID, 256, 0, stream>>>(
                zprev, sc_in, sh_in, off, deg, colS, zcur,
                Wpk + (size_t)l * 8192,
                b1 + l * 64, b2 + l * 64, gin_eps + l, gin_bias + l * 64,
                part_s, part_q);

        stat_reduce_kernel<<<64, 256, 0, stream>>>(
            part_s, part_q, gamma + l * 64, beta + l * 64, scale, shift);

        pool_kernel<<<NGRAPH, 256, 0, stream>>>(
            zcur, scale, shift, gstart, pooled, l * 64);

        zprev = (const void*)zcur;
        sc_in = scale;
        sh_in = shift;
    }

    proj_fused_kernel<<<NGRAPH, LDIM, 0, stream>>>(pooled, Wp1, bp1, Wp2, bp2, out);
}